// Round 1
// baseline (4908.874 us; speedup 1.0000x reference)
//
#include <hip/hip_runtime.h>
#include <hip/hip_bf16.h>

#define BB   128
#define SS   256
#define DD   512
#define HH   1024
#define NCC  128
#define NCLS 129
#define G4   4096   // 4*HH, gate-interleaved: j = hcol*4 + gate (f,i,g,o)

typedef __attribute__((ext_vector_type(8))) short  short8;
typedef __attribute__((ext_vector_type(4))) float  f32x4;

static __device__ __forceinline__ float sigm(float x)  { return 1.0f / (1.0f + __expf(-x)); }
static __device__ __forceinline__ float tanh_(float x) { return 1.0f - 2.0f / (__expf(2.0f * x) + 1.0f); }
static __device__ __forceinline__ unsigned short f2b(float v) {
    __hip_bfloat16 h = __float2bfloat16(v);
    return *reinterpret_cast<unsigned short*>(&h);
}
static __device__ __forceinline__ short8 ld16(const unsigned short* p) {
    return *reinterpret_cast<const short8*>(p);
}

// ---------------- zero-init C and h buffer 0 ----------------
__global__ void k_init(float* __restrict__ C, unsigned short* __restrict__ hb0) {
    int i = blockIdx.x * 256 + threadIdx.x;
    if (i < BB * HH) { C[i] = 0.0f; hb0[i] = 0; }
}

// ---------------- Wh -> bf16, transposed, gate-interleaved ----------------
// WhT[j][k] = W{gate}h[k][hcol], j = hcol*4 + gate.  LDS-tiled transpose.
__global__ void k_conv_wh(const float* __restrict__ Wfh, const float* __restrict__ Wih,
                          const float* __restrict__ Wgh, const float* __restrict__ Woh,
                          unsigned short* __restrict__ WhT) {
    __shared__ float t[32][33];
    int g = blockIdx.z;
    const float* W = (g == 0) ? Wfh : (g == 1) ? Wih : (g == 2) ? Wgh : Woh;
    int h0 = blockIdx.x * 32, k0 = blockIdx.y * 32;
    int tx = threadIdx.x & 31, ty = threadIdx.x >> 5;   // ty in 0..7
    for (int r = 0; r < 4; r++) {
        int k = ty + r * 8;
        t[k][tx] = W[(size_t)(k0 + k) * HH + h0 + tx];  // coalesced read
    }
    __syncthreads();
    for (int r = 0; r < 4; r++) {
        int hl = ty + r * 8;
        int j  = (h0 + hl) * 4 + g;
        WhT[(size_t)j * HH + k0 + tx] = f2b(t[tx][hl]); // coalesced write
    }
}

// ---------------- proj[c][j] = sum_d emb[c,d] * W{g}x[d,hcol] + b{g}[hcol] ----------------
__global__ void k_proj(const float* __restrict__ emb,
                       const float* __restrict__ Wfx, const float* __restrict__ Wix,
                       const float* __restrict__ Wgx, const float* __restrict__ Wox,
                       const float* __restrict__ bf_, const float* __restrict__ bi_,
                       const float* __restrict__ bg_, const float* __restrict__ bo_,
                       float* __restrict__ proj) {
    int c = blockIdx.y;
    int j = blockIdx.x * 256 + threadIdx.x;   // 0..4095
    int hcol = j >> 2, g = j & 3;
    const float* Wx = (g == 0) ? Wfx : (g == 1) ? Wix : (g == 2) ? Wgx : Wox;
    const float* bb = (g == 0) ? bf_ : (g == 1) ? bi_ : (g == 2) ? bg_ : bo_;
    float acc = bb[hcol];
    const float* er = emb + (size_t)c * DD;
    for (int d = 0; d < DD; d++) {
        acc += er[d] * Wx[(size_t)d * HH + hcol];
    }
    proj[(size_t)c * G4 + j] = acc;
}

// ---------------- one LSTM timestep ----------------
// gates[b][j] = sigmoid( proj[x[b,s]][j] + sum_k h[b][k] * WhT[j][k] )
// C = (g*i + C*f) * r ; h = o * tanh(C)
// Grid: (64, 2) x 256 threads. WG tile: 64 batch rows x 64 gate cols (16 hcols).
__global__ __launch_bounds__(256)
void k_step(int s, const int* __restrict__ x, const float* __restrict__ proj,
            const unsigned short* __restrict__ WhT,
            const unsigned short* __restrict__ h_in, unsigned short* __restrict__ h_out,
            float* __restrict__ hf32, float* __restrict__ C) {
    __shared__ float sg[64][68];     // sigmoided gates, [local b][local j], 16B-aligned rows
    __shared__ int   cls[64];
    int tid = threadIdx.x;
    int bx = blockIdx.x;             // N block (64 gate cols)
    int by = blockIdx.y;             // M block (64 batch rows)
    if (tid < 64) cls[tid] = x[(size_t)(by * 64 + tid) * SS + s];
    __syncthreads();

    int lane = tid & 63, w = tid >> 6;
    int wm = w >> 1, wn = w & 1;
    int m0 = by * 64 + wm * 32;
    int n0 = bx * 64 + wn * 32;
    int l15 = lane & 15, quad = lane >> 4;

    f32x4 acc[2][2];
    for (int mi = 0; mi < 2; mi++)
        for (int ni = 0; ni < 2; ni++)
            acc[mi][ni] = (f32x4){0.0f, 0.0f, 0.0f, 0.0f};

    const unsigned short* Ap = h_in + (size_t)(m0 + l15) * HH + quad * 8;
    const unsigned short* Bp = WhT  + (size_t)(n0 + l15) * HH + quad * 8;
    for (int k0 = 0; k0 < HH; k0 += 32) {
        short8 a0 = ld16(Ap + k0);
        short8 a1 = ld16(Ap + 16 * HH + k0);
        short8 b0 = ld16(Bp + k0);
        short8 b1 = ld16(Bp + 16 * HH + k0);
        acc[0][0] = __builtin_amdgcn_mfma_f32_16x16x32_bf16(a0, b0, acc[0][0], 0, 0, 0);
        acc[0][1] = __builtin_amdgcn_mfma_f32_16x16x32_bf16(a0, b1, acc[0][1], 0, 0, 0);
        acc[1][0] = __builtin_amdgcn_mfma_f32_16x16x32_bf16(a1, b0, acc[1][0], 0, 0, 0);
        acc[1][1] = __builtin_amdgcn_mfma_f32_16x16x32_bf16(a1, b1, acc[1][1], 0, 0, 0);
    }

    // epilogue: add proj, sigmoid, stash in LDS
    // D layout: row m = quad*4 + reg, col n = l15 (verified m89/m91)
    for (int mi = 0; mi < 2; mi++) {
        for (int ni = 0; ni < 2; ni++) {
            int nl = wn * 32 + ni * 16 + l15;
            int jg = bx * 64 + nl;
            for (int r = 0; r < 4; r++) {
                int ml = wm * 32 + mi * 16 + quad * 4 + r;
                float pre = acc[mi][ni][r] + proj[(size_t)cls[ml] * G4 + jg];
                sg[ml][nl] = sigm(pre);
            }
        }
    }
    __syncthreads();

    // pointwise update: 64 rows x 16 hcols per WG
    for (int it = 0; it < 4; it++) {
        int item = it * 256 + tid;            // 0..1023
        int bl = item >> 4, hl = item & 15;
        int b = by * 64 + bl, hc = bx * 16 + hl;
        float4 q = *reinterpret_cast<const float4*>(&sg[bl][hl * 4]);  // f,i,g,o
        float rr = (cls[bl] > 0) ? 1.0f : 0.0f;
        size_t idx = (size_t)b * HH + hc;
        float c_old = C[idx];
        float cn = (q.z * q.y + c_old * q.x) * rr;
        float hv = q.w * tanh_(cn);
        C[idx] = cn;
        h_out[idx] = f2b(hv);
        if (s == SS - 1) hf32[idx] = hv;
    }
}

// ---------------- final projection + log_softmax ----------------
__global__ void k_final(const float* __restrict__ hf32, const float* __restrict__ Wph,
                        const float* __restrict__ bp, float* __restrict__ out) {
    __shared__ float red[128];
    int b = blockIdx.x, c = threadIdx.x;    // 128 blocks x 128 threads
    const float* hr = hf32 + (size_t)b * HH;
    float acc = bp[c];
    for (int k = 0; k < HH; k++) acc += hr[k] * Wph[(size_t)k * NCC + c];
    red[c] = acc;
    __syncthreads();
    for (int st = 64; st > 0; st >>= 1) {
        if (c < st) red[c] = fmaxf(red[c], red[c + st]);
        __syncthreads();
    }
    float m = red[0];
    __syncthreads();
    red[c] = __expf(acc - m);
    __syncthreads();
    for (int st = 64; st > 0; st >>= 1) {
        if (c < st) red[c] += red[c + st];
        __syncthreads();
    }
    out[(size_t)b * NCC + c] = acc - m - __logf(red[0]);
}

extern "C" void kernel_launch(void* const* d_in, const int* in_sizes, int n_in,
                              void* d_out, int out_size, void* d_ws, size_t ws_size,
                              hipStream_t stream) {
    const int*   x   = (const int*)  d_in[0];
    const float* emb = (const float*)d_in[1];
    const float* Wfx = (const float*)d_in[2];
    const float* Wfh = (const float*)d_in[3];
    const float* bf_ = (const float*)d_in[4];
    const float* Wix = (const float*)d_in[5];
    const float* Wih = (const float*)d_in[6];
    const float* bi_ = (const float*)d_in[7];
    const float* Wgx = (const float*)d_in[8];
    const float* Wgh = (const float*)d_in[9];
    const float* bg_ = (const float*)d_in[10];
    const float* Wox = (const float*)d_in[11];
    const float* Woh = (const float*)d_in[12];
    const float* bo_ = (const float*)d_in[13];
    const float* Wph = (const float*)d_in[14];
    const float* bp_ = (const float*)d_in[15];
    float* out = (float*)d_out;

    char* ws = (char*)d_ws;
    unsigned short* WhT  = (unsigned short*)(ws);                    // 4096*1024*2 = 8 MB
    float*          proj = (float*)(ws + 8388608);                   // 129*4096*4 ≈ 2.02 MB
    float*          Cst  = (float*)(ws + 10502144);                  // 512 KB
    unsigned short* hb0  = (unsigned short*)(ws + 11026432);         // 256 KB
    unsigned short* hb1  = (unsigned short*)(ws + 11288576);         // 256 KB
    float*          hf32 = (float*)(ws + 11550720);                  // 512 KB
    // total ≈ 11.5 MB

    k_init<<<dim3(512), dim3(256), 0, stream>>>(Cst, hb0);
    k_conv_wh<<<dim3(32, 32, 4), dim3(256), 0, stream>>>(Wfh, Wih, Wgh, Woh, WhT);
    k_proj<<<dim3(16, NCLS), dim3(256), 0, stream>>>(emb, Wfx, Wix, Wgx, Wox,
                                                     bf_, bi_, bg_, bo_, proj);
    for (int s = 0; s < SS; s++) {
        unsigned short* hin  = (s & 1) ? hb1 : hb0;
        unsigned short* hout = (s & 1) ? hb0 : hb1;
        k_step<<<dim3(64, 2), dim3(256), 0, stream>>>(s, x, proj, WhT, hin, hout, hf32, Cst);
    }
    k_final<<<dim3(128), dim3(128), 0, stream>>>(hf32, Wph, bp_, out);
}